// Round 1
// baseline (1136.564 us; speedup 1.0000x reference)
//
#include <hip/hip_runtime.h>

#define HW_N 1048576
#define C_IN 64
#define K_CLS 4096
#define H1_N 256
#define NCLS_N 16

__device__ __forceinline__ float silu_f(float x) {
  return x / (1.0f + expf(-x));
}

// Degree-3 B-spline bases on the uniform grid g[j] = 0.4*(j-3) - 1, j=0..11.
// Produces the 8 surviving bases (matches reference recursion exactly).
__device__ __forceinline__ void bspline8(float x, float* b) {
  float t[11];
#pragma unroll
  for (int j = 0; j < 11; ++j) {
    float g0 = 0.4f * (float)(j - 3) - 1.0f;
    float g1 = 0.4f * (float)(j - 2) - 1.0f;
    t[j] = (x >= g0 && x < g1) ? 1.0f : 0.0f;
  }
#pragma unroll
  for (int k = 1; k <= 3; ++k) {
#pragma unroll 10
    for (int j = 0; j + k < 11; ++j) {
      float gj   = 0.4f * (float)(j - 3) - 1.0f;
      float gj1  = 0.4f * (float)(j - 2) - 1.0f;
      float gjk  = 0.4f * (float)(j + k - 3) - 1.0f;
      float gjk1 = 0.4f * (float)(j + k - 2) - 1.0f;
      float left  = (x - gj) / (gjk - gj);
      float right = (gjk1 - x) / (gjk1 - gj1);
      t[j] = left * t[j] + right * t[j + 1];
    }
  }
#pragma unroll
  for (int g = 0; g < 8; ++g) b[g] = t[g];
}

// ---------------- Kernel 1: segment sums + counts ----------------
__global__ __launch_bounds__(256) void segsum(
    const float* __restrict__ x, const int* __restrict__ cls,
    float* __restrict__ sums, int* __restrict__ cnt) {
  int tid = blockIdx.x * 256 + threadIdx.x;
  int stride = gridDim.x * 256;
  const float4* x4 = (const float4*)x;
  const int total = HW_N * 16;  // one float4 (4 features) per work item
  for (int t = tid; t < total; t += stride) {
    int r = t >> 4, q = t & 15;
    float4 v = x4[t];
    int c = cls[r];
    float* dst = sums + c * C_IN + q * 4;
    unsafeAtomicAdd(dst + 0, v.x);
    unsafeAtomicAdd(dst + 1, v.y);
    unsafeAtomicAdd(dst + 2, v.z);
    unsafeAtomicAdd(dst + 3, v.w);
    if (q == 0) atomicAdd(cnt + c, 1);
  }
}

// ---------------- Kernel 2: mean + KAN layer 1 (64 -> 256) ----------------
// Block: 256 threads (one per output o), 16 rows per block.
__global__ __launch_bounds__(256) void kan1(
    const float* __restrict__ sums, const int* __restrict__ cnt,
    const float* __restrict__ bw1, const float* __restrict__ sw1,
    const float* __restrict__ sc1, float* __restrict__ h) {
  __shared__ float s_silu[16][64];       // 4 KB
  __shared__ float s_bases[16][64][8];   // 32 KB
  int row0 = blockIdx.x * 16;
  int tid = threadIdx.x;

#pragma unroll
  for (int p = tid; p < 16 * 64; p += 256) {
    int r = p >> 6, i = p & 63;
    float c = fmaxf((float)cnt[row0 + r], 1.0f);
    float xv = sums[(row0 + r) * C_IN + i] / c;
    s_silu[r][i] = silu_f(xv);
    float b[8];
    bspline8(xv, b);
    float4* dst = (float4*)&s_bases[r][i][0];
    dst[0] = make_float4(b[0], b[1], b[2], b[3]);
    dst[1] = make_float4(b[4], b[5], b[6], b[7]);
  }
  __syncthreads();

  int o = tid;
  float acc[16];
#pragma unroll
  for (int r = 0; r < 16; ++r) acc[r] = 0.0f;

  for (int i = 0; i < C_IN; ++i) {
    float wb  = bw1[o * C_IN + i];
    float wsc = sc1[o * C_IN + i];
    const float4* wp = (const float4*)&sw1[(o * C_IN + i) * 8];
    float4 w0 = wp[0], w1 = wp[1];
    w0.x *= wsc; w0.y *= wsc; w0.z *= wsc; w0.w *= wsc;
    w1.x *= wsc; w1.y *= wsc; w1.z *= wsc; w1.w *= wsc;
#pragma unroll
    for (int r = 0; r < 16; ++r) {
      float sv = s_silu[r][i];
      const float4* bp = (const float4*)&s_bases[r][i][0];
      float4 b0 = bp[0], b1 = bp[1];
      float a = acc[r];
      a = fmaf(sv, wb, a);
      a = fmaf(b0.x, w0.x, a); a = fmaf(b0.y, w0.y, a);
      a = fmaf(b0.z, w0.z, a); a = fmaf(b0.w, w0.w, a);
      a = fmaf(b1.x, w1.x, a); a = fmaf(b1.y, w1.y, a);
      a = fmaf(b1.z, w1.z, a); a = fmaf(b1.w, w1.w, a);
      acc[r] = a;
    }
  }
#pragma unroll
  for (int r = 0; r < 16; ++r) h[(row0 + r) * H1_N + o] = acc[r];
}

// ---------------- Kernel 3: KAN layer 2 (256 -> 16) ----------------
// Block: 256 threads = (o in 0..15) x (rr in 0..15); 16 rows per block,
// input dimension processed in chunks of 64 staged in LDS.
__global__ __launch_bounds__(256) void kan2(
    const float* __restrict__ h,
    const float* __restrict__ bw2, const float* __restrict__ sw2,
    const float* __restrict__ sc2, float* __restrict__ out) {
  __shared__ float s_silu[16][65];    // padded: stride 65 -> no bank aliasing
  __shared__ float s_bases[16][516];  // padded: stride 516 floats (16B aligned)
  int row0 = blockIdx.x * 16;
  int tid = threadIdx.x;
  int o = tid & 15, rr = tid >> 4;
  float acc = 0.0f;

  for (int ic0 = 0; ic0 < H1_N; ic0 += 64) {
#pragma unroll
    for (int p = tid; p < 16 * 64; p += 256) {
      int r = p >> 6, i = p & 63;
      float xv = h[(row0 + r) * H1_N + ic0 + i];
      s_silu[r][i] = silu_f(xv);
      float b[8];
      bspline8(xv, b);
      float4* dst = (float4*)&s_bases[r][i * 8];
      dst[0] = make_float4(b[0], b[1], b[2], b[3]);
      dst[1] = make_float4(b[4], b[5], b[6], b[7]);
    }
    __syncthreads();

    for (int i = 0; i < 64; ++i) {
      int gi = ic0 + i;
      float wb  = bw2[o * H1_N + gi];
      float wsc = sc2[o * H1_N + gi];
      const float4* wp = (const float4*)&sw2[(o * H1_N + gi) * 8];
      float4 w0 = wp[0], w1 = wp[1];
      float sv = s_silu[rr][i];
      const float4* bp = (const float4*)&s_bases[rr][i * 8];
      float4 b0 = bp[0], b1 = bp[1];
      float sp = b0.x * w0.x + b0.y * w0.y + b0.z * w0.z + b0.w * w0.w
               + b1.x * w1.x + b1.y * w1.y + b1.z * w1.z + b1.w * w1.w;
      acc = fmaf(sv, wb, acc);
      acc = fmaf(sp, wsc, acc);
    }
    __syncthreads();
  }
  out[(row0 + rr) * NCLS_N + o] = acc;
}

extern "C" void kernel_launch(void* const* d_in, const int* in_sizes, int n_in,
                              void* d_out, int out_size, void* d_ws, size_t ws_size,
                              hipStream_t stream) {
  const float* x   = (const float*)d_in[0];
  const int*   cls = (const int*)d_in[1];
  const float* bw1 = (const float*)d_in[2];
  const float* sw1 = (const float*)d_in[3];
  const float* sc1 = (const float*)d_in[4];
  const float* bw2 = (const float*)d_in[5];
  const float* sw2 = (const float*)d_in[6];
  const float* sc2 = (const float*)d_in[7];
  float* out = (float*)d_out;

  float* sums = (float*)d_ws;                    // K*C floats
  int*   cnt  = (int*)(sums + K_CLS * C_IN);     // K ints
  float* h    = (float*)(cnt + K_CLS);           // K*H1 floats

  // zero accumulators (must happen every call: atomics accumulate)
  hipMemsetAsync(d_ws, 0, (K_CLS * C_IN + K_CLS) * sizeof(float), stream);

  segsum<<<2048, 256, 0, stream>>>(x, cls, sums, cnt);
  kan1<<<K_CLS / 16, 256, 0, stream>>>(sums, cnt, bw1, sw1, sc1, h);
  kan2<<<K_CLS / 16, 256, 0, stream>>>(h, bw2, sw2, sc2, out);
}

// Round 2
// 557.243 us; speedup vs baseline: 2.0396x; 2.0396x over previous
//
#include <hip/hip_runtime.h>

#define HW_N 1048576
#define C_IN 64
#define K_CLS 4096
#define H1_N 256
#define NCLS_N 16
#define RG_N 32           // row groups for partial sums
#define ROWS_PER_RG (HW_N / RG_N)
#define CNT_BLOCKS 64

__device__ __forceinline__ float silu_f(float x) {
  return x / (1.0f + expf(-x));
}

// Degree-3 B-spline bases on the uniform grid g[j] = 0.4*(j-3) - 1, j=0..11.
__device__ __forceinline__ void bspline8(float x, float* b) {
  float t[11];
#pragma unroll
  for (int j = 0; j < 11; ++j) {
    float g0 = 0.4f * (float)(j - 3) - 1.0f;
    float g1 = 0.4f * (float)(j - 2) - 1.0f;
    t[j] = (x >= g0 && x < g1) ? 1.0f : 0.0f;
  }
#pragma unroll
  for (int k = 1; k <= 3; ++k) {
#pragma unroll 10
    for (int j = 0; j + k < 11; ++j) {
      float gj   = 0.4f * (float)(j - 3) - 1.0f;
      float gj1  = 0.4f * (float)(j - 2) - 1.0f;
      float gjk  = 0.4f * (float)(j + k - 3) - 1.0f;
      float gjk1 = 0.4f * (float)(j + k - 2) - 1.0f;
      float left  = (x - gj) / (gjk - gj);
      float right = (gjk1 - x) / (gjk1 - gj1);
      t[j] = left * t[j] + right * t[j + 1];
    }
  }
#pragma unroll
  for (int g = 0; g < 8; ++g) b[g] = t[g];
}

// ---------------- Kernel 1a: per-block cluster counts ----------------
__global__ __launch_bounds__(1024) void segcnt(
    const int* __restrict__ cls, int* __restrict__ pcnt) {
  __shared__ int chist[K_CLS];  // 16 KB
  int tid = threadIdx.x;
  for (int p = tid; p < K_CLS; p += 1024) chist[p] = 0;
  __syncthreads();
  int rows = HW_N / CNT_BLOCKS;
  int rowbase = blockIdx.x * rows;
  for (int r = rowbase + tid; r < rowbase + rows; r += 1024)
    atomicAdd(&chist[cls[r]], 1);
  __syncthreads();
  int* dst = pcnt + blockIdx.x * K_CLS;
  for (int p = tid; p < K_CLS; p += 1024) dst[p] = chist[p];
}

__global__ __launch_bounds__(256) void cnt_reduce(
    const int* __restrict__ pcnt, int* __restrict__ cnt) {
  int c = blockIdx.x * 256 + threadIdx.x;
  int s = 0;
#pragma unroll
  for (int b = 0; b < CNT_BLOCKS; ++b) s += pcnt[b * K_CLS + c];
  cnt[c] = s;
}

// ---------------- Kernel 1b: partial segment sums (LDS-privatized) -------
// Grid = 4 feature-chunks x 2 cluster-halves x RG_N row-groups = 256 blocks.
// Each block owns hist[16][2048] fp32 = 128 KB LDS.
__global__ __launch_bounds__(1024) void segsum_part(
    const float* __restrict__ x, const int* __restrict__ cls,
    float* __restrict__ partials) {
  __shared__ float hist[16][2048];  // 128 KB, f-major: bank = cl & 31
  int b = blockIdx.x;
  int chunk = b >> 6;          // 0..3 : features [chunk*16, chunk*16+16)
  int half  = (b >> 5) & 1;    // 0..1 : clusters [half*2048, half*2048+2048)
  int rg    = b & 31;          // 0..31: rows [rg*32768, ...)
  int tid = threadIdx.x;

  float* hflat = &hist[0][0];
  for (int p = tid; p < 16 * 2048; p += 1024) hflat[p] = 0.0f;
  __syncthreads();

  int rowbase = rg * ROWS_PER_RG;
  for (int r = rowbase + tid; r < rowbase + ROWS_PER_RG; r += 1024) {
    int c = cls[r];
    if ((c >> 11) != half) continue;
    int cl = c & 2047;
    const float4* xp = (const float4*)(x + (size_t)r * C_IN + chunk * 16);
    float v[16];
    *(float4*)&v[0]  = xp[0];
    *(float4*)&v[4]  = xp[1];
    *(float4*)&v[8]  = xp[2];
    *(float4*)&v[12] = xp[3];
#pragma unroll
    for (int fl = 0; fl < 16; ++fl) atomicAdd(&hist[fl][cl], v[fl]);
  }
  __syncthreads();

  float* dst = partials + (size_t)b * (16 * 2048);
  for (int p = tid; p < 16 * 2048; p += 1024) dst[p] = hflat[p];
}

// partials[(chunk*2+half)*RG_N + rg][fl][cl]  ->  sums[c][f]
__global__ __launch_bounds__(256) void segsum_reduce(
    const float* __restrict__ partials, float* __restrict__ sums) {
  int t = blockIdx.x * 256 + threadIdx.x;  // t = f*4096 + c
  int f = t >> 12;
  int c = t & 4095;
  int chunk = f >> 4, fl = f & 15;
  int half = c >> 11, cl = c & 2047;
  const float* p = partials +
      (size_t)((chunk * 2 + half) * RG_N) * (16 * 2048) + fl * 2048 + cl;
  float s = 0.0f;
#pragma unroll
  for (int rg = 0; rg < RG_N; ++rg) s += p[(size_t)rg * (16 * 2048)];
  sums[c * C_IN + f] = s;
}

// ---------------- Kernel 2: mean + KAN layer 1 (64 -> 256) ----------------
// 512 blocks x 256 threads (one per output o), 8 rows per block.
__global__ __launch_bounds__(256) void kan1(
    const float* __restrict__ sums, const int* __restrict__ cnt,
    const float* __restrict__ bw1, const float* __restrict__ sw1,
    const float* __restrict__ sc1, float* __restrict__ h) {
  __shared__ float s_silu[8][64];      // 2 KB
  __shared__ float s_bases[8][64][8];  // 16 KB
  int row0 = blockIdx.x * 8;
  int tid = threadIdx.x;

  for (int p = tid; p < 8 * 64; p += 256) {
    int r = p >> 6, i = p & 63;
    float c = fmaxf((float)cnt[row0 + r], 1.0f);
    float xv = sums[(row0 + r) * C_IN + i] / c;
    s_silu[r][i] = silu_f(xv);
    float b[8];
    bspline8(xv, b);
    float4* dst = (float4*)&s_bases[r][i][0];
    dst[0] = make_float4(b[0], b[1], b[2], b[3]);
    dst[1] = make_float4(b[4], b[5], b[6], b[7]);
  }
  __syncthreads();

  int o = tid;
  float acc[8];
#pragma unroll
  for (int r = 0; r < 8; ++r) acc[r] = 0.0f;

  for (int i = 0; i < C_IN; ++i) {
    float wb  = bw1[o * C_IN + i];
    float wsc = sc1[o * C_IN + i];
    const float4* wp = (const float4*)&sw1[(o * C_IN + i) * 8];
    float4 w0 = wp[0], w1 = wp[1];
    w0.x *= wsc; w0.y *= wsc; w0.z *= wsc; w0.w *= wsc;
    w1.x *= wsc; w1.y *= wsc; w1.z *= wsc; w1.w *= wsc;
#pragma unroll
    for (int r = 0; r < 8; ++r) {
      float sv = s_silu[r][i];
      const float4* bp = (const float4*)&s_bases[r][i][0];
      float4 b0 = bp[0], b1 = bp[1];
      float a = acc[r];
      a = fmaf(sv, wb, a);
      a = fmaf(b0.x, w0.x, a); a = fmaf(b0.y, w0.y, a);
      a = fmaf(b0.z, w0.z, a); a = fmaf(b0.w, w0.w, a);
      a = fmaf(b1.x, w1.x, a); a = fmaf(b1.y, w1.y, a);
      a = fmaf(b1.z, w1.z, a); a = fmaf(b1.w, w1.w, a);
      acc[r] = a;
    }
  }
#pragma unroll
  for (int r = 0; r < 8; ++r) h[(row0 + r) * H1_N + o] = acc[r];
}

// ---------------- Kernel 3: KAN layer 2 (256 -> 16) ----------------
__global__ __launch_bounds__(256) void kan2(
    const float* __restrict__ h,
    const float* __restrict__ bw2, const float* __restrict__ sw2,
    const float* __restrict__ sc2, float* __restrict__ out) {
  __shared__ float s_silu[16][65];
  __shared__ float s_bases[16][516];
  int row0 = blockIdx.x * 16;
  int tid = threadIdx.x;
  int o = tid & 15, rr = tid >> 4;
  float acc = 0.0f;

  for (int ic0 = 0; ic0 < H1_N; ic0 += 64) {
    for (int p = tid; p < 16 * 64; p += 256) {
      int r = p >> 6, i = p & 63;
      float xv = h[(row0 + r) * H1_N + ic0 + i];
      s_silu[r][i] = silu_f(xv);
      float b[8];
      bspline8(xv, b);
      float4* dst = (float4*)&s_bases[r][i * 8];
      dst[0] = make_float4(b[0], b[1], b[2], b[3]);
      dst[1] = make_float4(b[4], b[5], b[6], b[7]);
    }
    __syncthreads();

    for (int i = 0; i < 64; ++i) {
      int gi = ic0 + i;
      float wb  = bw2[o * H1_N + gi];
      float wsc = sc2[o * H1_N + gi];
      const float4* wp = (const float4*)&sw2[(o * H1_N + gi) * 8];
      float4 w0 = wp[0], w1 = wp[1];
      float sv = s_silu[rr][i];
      const float4* bp = (const float4*)&s_bases[rr][i * 8];
      float4 b0 = bp[0], b1 = bp[1];
      float sp = b0.x * w0.x + b0.y * w0.y + b0.z * w0.z + b0.w * w0.w
               + b1.x * w1.x + b1.y * w1.y + b1.z * w1.z + b1.w * w1.w;
      acc = fmaf(sv, wb, acc);
      acc = fmaf(sp, wsc, acc);
    }
    __syncthreads();
  }
  out[(row0 + rr) * NCLS_N + o] = acc;
}

extern "C" void kernel_launch(void* const* d_in, const int* in_sizes, int n_in,
                              void* d_out, int out_size, void* d_ws, size_t ws_size,
                              hipStream_t stream) {
  const float* x   = (const float*)d_in[0];
  const int*   cls = (const int*)d_in[1];
  const float* bw1 = (const float*)d_in[2];
  const float* sw1 = (const float*)d_in[3];
  const float* sc1 = (const float*)d_in[4];
  const float* bw2 = (const float*)d_in[5];
  const float* sw2 = (const float*)d_in[6];
  const float* sc2 = (const float*)d_in[7];
  float* out = (float*)d_out;

  float* partials = (float*)d_ws;                         // 256*32768 floats = 32 MB
  int*   pcnt = (int*)(partials + 256 * 16 * 2048);       // 64*4096 ints = 1 MB
  float* sums = (float*)(pcnt + CNT_BLOCKS * K_CLS);      // 1 MB
  int*   cnt  = (int*)(sums + K_CLS * C_IN);              // 16 KB
  float* h    = (float*)(cnt + K_CLS);                    // 4 MB

  segcnt<<<CNT_BLOCKS, 1024, 0, stream>>>(cls, pcnt);
  segsum_part<<<256, 1024, 0, stream>>>(x, cls, partials);
  cnt_reduce<<<K_CLS / 256, 256, 0, stream>>>(pcnt, cnt);
  segsum_reduce<<<(C_IN * K_CLS) / 256, 256, 0, stream>>>(partials, sums);
  kan1<<<K_CLS / 8, 256, 0, stream>>>(sums, cnt, bw1, sw1, sc1, h);
  kan2<<<K_CLS / 16, 256, 0, stream>>>(h, bw2, sw2, sc2, out);
}